// Round 7
// baseline (436.657 us; speedup 1.0000x reference)
//
#include <hip/hip_runtime.h>
#include <math.h>

#define B_    128
#define CIN   128
#define TIN   2500
#define COUT  64
#define KW    27
#define TOUT  625
#define TPAD  640   // padded t extent for bf16 q/k/v planes
#define CTT   32    // conv t-tile
#define GROWS 152   // conv staging rows (span 4*31+27=151, pad to 152)

typedef __bf16 bf16x8 __attribute__((ext_vector_type(8)));
typedef float  f32x4  __attribute__((ext_vector_type(4)));
typedef float  f32x16 __attribute__((ext_vector_type(16)));

__device__ __forceinline__ unsigned short f32_to_bf16_rne(float v) {
    unsigned u = __float_as_uint(v);
    u += 0x7FFFu + ((u >> 16) & 1u);
    return (unsigned short)(u >> 16);
}

__device__ __forceinline__ f32x4 mfma_bf16(bf16x8 a, bf16x8 b, f32x4 c) {
    return __builtin_amdgcn_mfma_f32_16x16x32_bf16(a, b, c, 0, 0, 0);
}

// ---------------------------------------------------------------------------
// K0 (prep): blocks 0-63 (o=blk): alpha + scA/scB, and EXPANDED A-fragments
//   for the conv 32x32x16 MFMA: Afrag4[(kk*4+ks)*256 + ch*128 + oh*64 + lane]
//   = uint4 of 8 bf16 (+-1), lane=(kg1*32+lo), half h = sign of
//   w[o=oh*32+lo][c = ch*64+ks*16+kg1*8+h] at tap kk (v>0 -> +1 else -1).
//   442KB total, L2-resident, read by every conv block -> no LDS LUT needed.
//   Blocks 64-66: wq/wk/wv -> bf16 hi/lo planes [o][c]; block 67: wo hi/lo.
// ---------------------------------------------------------------------------
__global__ void prep_kernel(const float* __restrict__ w,
                            const float* __restrict__ wq, const float* __restrict__ wk,
                            const float* __restrict__ wv, const float* __restrict__ wo,
                            const float* __restrict__ conv_b, const float* __restrict__ gamma_,
                            const float* __restrict__ beta_, const float* __restrict__ mean_,
                            const float* __restrict__ var_,
                            uint4* __restrict__ Afrag4,
                            unsigned short* __restrict__ w3_h, unsigned short* __restrict__ w3_l,
                            unsigned short* __restrict__ wo_h, unsigned short* __restrict__ wo_l,
                            float* __restrict__ scA, float* __restrict__ scB) {
    int blk = blockIdx.x, tid = threadIdx.x;
    if (blk < 64) {
        __shared__ float red[256];
        const float* wrow = w + (size_t)blk * (CIN * KW);
        float s = 0.f;
        for (int idx = tid; idx < CIN * KW; idx += 256) s += fabsf(wrow[idx]);
        red[tid] = s;
        __syncthreads();
        for (int st = 128; st > 0; st >>= 1) {
            if (tid < st) red[tid] += red[tid + st];
            __syncthreads();
        }
        if (tid == 0) {
            float alpha = red[0] / (float)(CIN * KW);
            float inv = rsqrtf(var_[blk] + 1e-5f);
            float G = gamma_[blk] * inv;
            scA[blk] = alpha * G;
            scB[blk] = (conv_b[blk] - mean_[blk]) * G + beta_[blk];
        }
        int oh = blk >> 5, lo = blk & 31;
        for (int t = tid; t < 27 * 16; t += 256) {
            int kk = t >> 4;
            int rem = t & 15;
            int ch = rem >> 3, ks = (rem >> 1) & 3, kg1 = rem & 1;
            unsigned wd[4];
#pragma unroll
            for (int jj = 0; jj < 4; ++jj) {
                int c0 = ch * 64 + ks * 16 + kg1 * 8 + 2 * jj;
                unsigned lo_h = (wrow[c0 * KW + kk]       > 0.f) ? 0x3F80u : 0xBF80u;
                unsigned hi_h = (wrow[(c0 + 1) * KW + kk] > 0.f) ? 0x3F80u : 0xBF80u;
                wd[jj] = lo_h | (hi_h << 16);
            }
            Afrag4[(kk * 4 + ks) * 256 + ch * 128 + oh * 64 + kg1 * 32 + lo] =
                make_uint4(wd[0], wd[1], wd[2], wd[3]);
        }
    } else if (blk < 67) {
        const float* srcs[3] = {wq, wk, wv};
        const float* src = srcs[blk - 64];
        unsigned short* dh = w3_h + (size_t)(blk - 64) * 4096;
        unsigned short* dl = w3_l + (size_t)(blk - 64) * 4096;
        for (int idx = tid; idx < 4096; idx += 256) {
            float v = src[idx];
            unsigned short h = f32_to_bf16_rne(v);
            float hf = __uint_as_float((unsigned)h << 16);
            dh[idx] = h;
            dl[idx] = f32_to_bf16_rne(v - hf);
        }
    } else {
        for (int idx = tid; idx < 4096; idx += 256) {
            float v = wo[idx];
            unsigned short h = f32_to_bf16_rne(v);
            float hf = __uint_as_float((unsigned)h << 16);
            wo_h[idx] = h;
            wo_l[idx] = f32_to_bf16_rne(v - hf);
        }
    }
}

// ---------------------------------------------------------------------------
// K1: binarized conv1d + BN/ELU -> y, fused q/k/v projections.
//   This round: the sign-LUT LDS expansion (8x ds_read_b64 per kk per wave,
//   half of a ~90%-saturated LDS port) is replaced by coalesced L2-resident
//   global loads of precomputed A-fragments (1-deep prefetch). LDS demand
//   in the K-loop halves; math bit-identical.
// ---------------------------------------------------------------------------
__global__ __launch_bounds__(256, 4) void conv_kernel(
    const float* __restrict__ x, const uint4* __restrict__ Afrag4,
    const float* __restrict__ scA, const float* __restrict__ scB,
    const unsigned short* __restrict__ w3_h, const unsigned short* __restrict__ w3_l,
    float* __restrict__ y_out,
    unsigned short* __restrict__ q_h, unsigned short* __restrict__ k_h,
    unsigned short* __restrict__ vT_h)
{
    __shared__ __align__(16) unsigned short xhi[GROWS * 128];  // 38912 B
    // overlays on xhi (valid only after the post-K-loop barrier):
    unsigned short* y_sh = xhi;            // [32][64] bf16, c8-swizzled
    unsigned short* s_sh = xhi + 2048;     // spike plane, same layout
    unsigned short* q_sh = xhi + 4096;     // [32][64] bf16, o8-swizzled
    unsigned short* k_sh = xhi + 6144;
    unsigned short* v_sh = xhi + 8192;     // [64][32] bf16, t8-swizzled
    float* part_sh = (float*)(xhi + 10240);  // 2048 f32 (c-half partials)

    int tid = threadIdx.x;
    // XCD-aware remap (2560 wgs, 2560%8==0 -> bijective)
    int id = blockIdx.x + 20 * blockIdx.y;
    int nid = (id & 7) * 320 + (id >> 3);
    int b = nid / 20;
    int t0 = (nid - b * 20) * CTT;

    // ---- stage x (hi bf16, RNE): task = (c8, gl); 8 loads -> one b128 ----
    const float* xb = x + (size_t)b * CIN * TIN;
    int gbase = 4 * t0 - 13;
    for (int task = tid; task < 16 * GROWS; task += 256) {
        int c8 = task / GROWS, gl = task - c8 * GROWS;
        int g = gbase + gl;
        bool valid = (gl < 151) && ((unsigned)g < (unsigned)TIN);
        float vs[8];
#pragma unroll
        for (int j = 0; j < 8; j++)
            vs[j] = valid ? xb[(size_t)(c8 * 8 + j) * TIN + g] : 0.f;
        union { unsigned u[4]; uint4 q; } H;
#pragma unroll
        for (int j = 0; j < 4; j++) {
            unsigned short h0 = f32_to_bf16_rne(vs[2 * j]);
            unsigned short h1 = f32_to_bf16_rne(vs[2 * j + 1]);
            H.u[j] = (unsigned)h0 | ((unsigned)h1 << 16);
        }
        int c8p = c8 ^ ((gl >> 2) & 15);
        *(uint4*)(xhi + gl * 128 + c8p * 8) = H.q;
    }
    __syncthreads();

    // ---- MFMA K-loop (32x32x16): wave = (oh = o-half, ch = c-half) ----
    int wave = tid >> 6, lane = tid & 63;
    int oh = wave & 1, ch = wave >> 1;
    int o0w = oh * 32;
    int lo = lane & 31;        // A: o-offset; B: t-offset
    int kg1 = lane >> 5;       // k-octet within K=16

    f32x16 acc = {0.f};
    const uint4* afb = Afrag4 + ch * 128 + oh * 64 + lane;

    uint4 a4[4], n4[4];
#pragma unroll
    for (int ks = 0; ks < 4; ++ks) a4[ks] = afb[ks * 256];

#pragma unroll 1
    for (int kk = 0; kk < KW; ++kk) {
        if (kk < KW - 1) {
#pragma unroll
            for (int ks = 0; ks < 4; ++ks) n4[ks] = afb[((kk + 1) * 4 + ks) * 256];
        }
        int gl = 4 * lo + kk;
        int rot = (gl >> 2) & 15;
        const unsigned short* xr = xhi + gl * 128;
#pragma unroll
        for (int ks = 0; ks < 4; ++ks) {
            int oct = ch * 8 + ks * 2 + kg1;
            int c8p = oct ^ rot;
            bf16x8 bx = *(const bf16x8*)(xr + c8p * 8);
            union { uint4 q; bf16x8 v; } A;
            A.q = a4[ks];
            acc = __builtin_amdgcn_mfma_f32_32x32x16_bf16(A.v, bx, acc, 0, 0, 0);
        }
#pragma unroll
        for (int ks = 0; ks < 4; ++ks) a4[ks] = n4[ks];
    }
    __syncthreads();     // all waves done reading xhi -> overlays valid

    // ---- c-half reconcile: ch=1 publishes partials ----
    if (ch == 1) {
        float* p = part_sh + oh * 1024 + lane;
#pragma unroll
        for (int r = 0; r < 16; ++r) p[r * 64] = acc[r];
    }
    __syncthreads();

    // ---- ch=0: combine, BN/ELU, y_out store, pack y+spike (pads -> 0) ----
    if (ch == 0) {
        const float* p = part_sh + oh * 1024 + lane;
        int t_g = t0 + lo;
        bool tv = t_g < TOUT;
#pragma unroll
        for (int g2 = 0; g2 < 4; ++g2) {
            unsigned long long yp = 0, sp = 0;
#pragma unroll
            for (int j = 0; j < 4; ++j) {
                int r = g2 * 4 + j;
                float v = acc[r] + p[r * 64];
                int o = o0w + 4 * kg1 + 8 * g2 + j;
                float s = v * scA[o] + scB[o];
                float yv = s > 0.f ? s : expm1f(s);
                if (tv) {
                    y_out[((size_t)b * COUT + o) * TOUT + t_g] = yv;
                    yp |= (unsigned long long)f32_to_bf16_rne(yv) << (16 * j);
                    if (yv > 0.f) sp |= 0x3F80ull << (16 * j);
                }
            }
            int c8 = 4 * oh + g2;
            int idx = lo * 64 + ((c8 ^ (lo & 7)) << 3) + 4 * kg1;
            *(unsigned long long*)(y_sh + idx) = yp;
            *(unsigned long long*)(s_sh + idx) = sp;
        }
    }
    __syncthreads();

    // ---- fused projections: wave -> o-slice 16 ----
    int quad = lane >> 4, col = lane & 15;
    int o0 = wave * 16;
    bf16x8 sf[2][2], yf[2][2];           // [tt][ks] B-fragments
#pragma unroll
    for (int tt = 0; tt < 2; ++tt)
#pragma unroll
        for (int ks = 0; ks < 2; ++ks) {
            int tl = tt * 16 + col;
            int idx = tl * 64 + (((ks * 4 + quad) ^ (tl & 7)) << 3);
            sf[tt][ks] = *(const bf16x8*)(s_sh + idx);
            yf[tt][ks] = *(const bf16x8*)(y_sh + idx);
        }
    size_t wofs = (size_t)(o0 + col) * 64 + quad * 8;
    f32x4 qa[2], ka[2], va[2];
#pragma unroll
    for (int tt = 0; tt < 2; ++tt) {
        qa[tt] = (f32x4){0.f, 0.f, 0.f, 0.f};
        ka[tt] = (f32x4){0.f, 0.f, 0.f, 0.f};
        va[tt] = (f32x4){0.f, 0.f, 0.f, 0.f};
    }
#pragma unroll
    for (int ks = 0; ks < 2; ++ks) {
        bf16x8 aqh = *(const bf16x8*)(w3_h + wofs + ks * 32);
        bf16x8 aql = *(const bf16x8*)(w3_l + wofs + ks * 32);
        bf16x8 akh = *(const bf16x8*)(w3_h + 4096 + wofs + ks * 32);
        bf16x8 akl = *(const bf16x8*)(w3_l + 4096 + wofs + ks * 32);
        bf16x8 avh = *(const bf16x8*)(w3_h + 8192 + wofs + ks * 32);
        bf16x8 avl = *(const bf16x8*)(w3_l + 8192 + wofs + ks * 32);
#pragma unroll
        for (int tt = 0; tt < 2; ++tt) {
            qa[tt] = mfma_bf16(aqh, sf[tt][ks], qa[tt]);
            qa[tt] = mfma_bf16(aql, sf[tt][ks], qa[tt]);
            ka[tt] = mfma_bf16(akh, sf[tt][ks], ka[tt]);
            ka[tt] = mfma_bf16(akl, sf[tt][ks], ka[tt]);
            va[tt] = mfma_bf16(avh, yf[tt][ks], va[tt]);
            va[tt] = mfma_bf16(avl, yf[tt][ks], va[tt]);
        }
    }
    // q/k -> LDS [t][o] (o8-swizzled, 8B packs); v -> v_sh [c][t] (t8-swz)
    int c8w = (o0 >> 3) + (quad >> 1);
    int cof = (quad & 1) * 4;
#pragma unroll
    for (int tt = 0; tt < 2; ++tt) {
        int tl = tt * 16 + col;
        int idx = tl * 64 + ((c8w ^ (tl & 7)) << 3) + cof;
        unsigned long long qp = 0, kp = 0;
#pragma unroll
        for (int r = 0; r < 4; ++r) {
            qp |= (unsigned long long)f32_to_bf16_rne(qa[tt][r]) << (16 * r);
            kp |= (unsigned long long)f32_to_bf16_rne(ka[tt][r]) << (16 * r);
        }
        *(unsigned long long*)(q_sh + idx) = qp;
        *(unsigned long long*)(k_sh + idx) = kp;
#pragma unroll
        for (int r = 0; r < 4; ++r) {
            int c = o0 + quad * 4 + r;
            int vidx = c * 32 + (((tt * 2 + (col >> 3)) ^ quad) << 3) + (col & 7);
            v_sh[vidx] = f32_to_bf16_rne(va[tt][r]);
        }
    }
    __syncthreads();

    // ---- cooperative coalesced stores ----
    {
        int tl = tid >> 3, seg = tid & 7;
        int idx = tl * 64 + ((seg ^ (tl & 7)) << 3);
        uint4 qv = *(const uint4*)(q_sh + idx);
        uint4 kv = *(const uint4*)(k_sh + idx);
        size_t go = ((size_t)b * TPAD + t0 + tl) * 64 + seg * 8;
        *(uint4*)(q_h + go) = qv;
        *(uint4*)(k_h + go) = kv;
        int c = tid >> 2, ts = tid & 3;
        int vidx = c * 32 + ((ts ^ ((c >> 2) & 3)) << 3);
        uint4 vv = *(const uint4*)(v_sh + vidx);
        *(uint4*)(vT_h + ((size_t)b * 64 + c) * TPAD + t0 + ts * 8) = vv;
    }
}

// ---------------------------------------------------------------------------
// K2: MFMA attention per (b, 16-t tile), 512 threads / 8 waves (unchanged R6:
//   register scores, shfl+partial-LDS softmax, bf16-only P in LDS, 4 blk/CU).
// ---------------------------------------------------------------------------
__global__ __launch_bounds__(512, 8) void attn_kernel(
    const unsigned short* __restrict__ q_h, const unsigned short* __restrict__ k_h,
    const unsigned short* __restrict__ vT_h, const float* __restrict__ y,
    const unsigned short* __restrict__ wo_h, const unsigned short* __restrict__ wo_l,
    float* __restrict__ out)
{
    __shared__ __align__(16) unsigned short P_lds[16 * 648];  // 20736 B (bf16 P)
    __shared__ __align__(16) float pmax_sh[16 * 8];           // 512 B [t][wave]
    __shared__ __align__(16) float psum_sh[16 * 8];           // 512 B [t][wave]
    __shared__ float ctx_sh[2 * 64 * 17];                     // 8704 B => 30464 total

    int tid = threadIdx.x;
    int id = blockIdx.x + 40 * blockIdx.y;
    int nid = (id & 7) * 640 + (id >> 3);
    int b = nid / 40;
    int t0 = (nid - b * 40) * 16;

    int wave = tid >> 6, lane = tid & 63;
    int quad = lane >> 4, nlo = lane & 15;

    // ---- QK^T: wave w covers s in [w*80, (w+1)*80); scores stay in regs ----
    const unsigned short* qb = q_h + ((size_t)b * TPAD + t0 + nlo) * 64 + quad * 8;
    bf16x8 qa0 = *(const bf16x8*)(qb);
    bf16x8 qa1 = *(const bf16x8*)(qb + 32);
    const unsigned short* kbase = k_h + (size_t)b * TPAD * 64 + quad * 8;
    f32x4 acc[5];
#pragma unroll 5
    for (int nt = 0; nt < 5; ++nt) {
        int s = wave * 80 + nt * 16 + nlo;
        const unsigned short* krow = kbase + (size_t)s * 64;
        bf16x8 kb0 = *(const bf16x8*)(krow);
        bf16x8 kb1 = *(const bf16x8*)(krow + 32);
        f32x4 a = {0.f, 0.f, 0.f, 0.f};
        a = mfma_bf16(qa0, kb0, a);
        a = mfma_bf16(qa1, kb1, a);
        acc[nt] = a;
    }

    // ---- row max: lane-local over nt (masked), shfl over 16-lane group ----
    float rmx[4] = {-3.0e38f, -3.0e38f, -3.0e38f, -3.0e38f};
#pragma unroll
    for (int nt = 0; nt < 5; ++nt) {
        int s = wave * 80 + nt * 16 + nlo;
        bool v = s < TOUT;
#pragma unroll
        for (int r = 0; r < 4; ++r) {
            float sc = acc[nt][r] * 0.125f;
            acc[nt][r] = sc;
            if (v) rmx[r] = fmaxf(rmx[r], sc);
        }
    }
#pragma unroll
    for (int off = 1; off < 16; off <<= 1)
#pragma unroll
        for (int r = 0; r < 4; ++r) rmx[r] = fmaxf(rmx[r], __shfl_xor(rmx[r], off));
    if (nlo == 0) {
#pragma unroll
        for (int r = 0; r < 4; ++r) pmax_sh[(quad * 4 + r) * 8 + wave] = rmx[r];
    }
    __syncthreads();

    // ---- final row max (broadcast float4 reads), exp in regs, partial sum ----
    float rsum[4] = {0.f, 0.f, 0.f, 0.f};
    float rowm[4];
#pragma unroll
    for (int r = 0; r < 4; ++r) {
        const float4* pm = (const float4*)&pmax_sh[(quad * 4 + r) * 8];
        float4 a = pm[0], c = pm[1];
        rowm[r] = fmaxf(fmaxf(fmaxf(a.x, a.y), fmaxf(a.z, a.w)),
                        fmaxf(fmaxf(c.x, c.y), fmaxf(c.z, c.w)));
    }
#pragma unroll
    for (int nt = 0; nt < 5; ++nt) {
        int s = wave * 80 + nt * 16 + nlo;
        bool v = s < TOUT;
#pragma unroll
        for (int r = 0; r < 4; ++r) {
            float e = v ? __expf(acc[nt][r] - rowm[r]) : 0.f;
            acc[nt][r] = e;
            rsum[r] += e;
        }
    }
#pragma unroll
    for (int off = 1; off < 16; off <<= 1)
#pragma unroll
        for (int r = 0; r < 4; ++r) rsum[r] += __shfl_xor(rsum[r], off);
    if (nlo == 0) {
#pragma unroll
        for (int r = 0; r < 4; ++r) psum_sh[(quad * 4 + r) * 8 + wave] = rsum[r];
    }

    // ---- store P bf16 into LDS [t][s], stride 648 halves ----
    unsigned short* pw = P_lds;
#pragma unroll
    for (int nt = 0; nt < 5; ++nt) {
        int s = wave * 80 + nt * 16 + nlo;
#pragma unroll
        for (int r = 0; r < 4; ++r)
            pw[(quad * 4 + r) * 648 + s] = f32_to_bf16_rne(acc[nt][r]);
    }
    __syncthreads();

    // ---- rden for this lane's rows (t = quad*4+r) ----
    float rden_r[4];
#pragma unroll
    for (int r = 0; r < 4; ++r) {
        const float4* ps = (const float4*)&psum_sh[(quad * 4 + r) * 8];
        float4 a = ps[0], c = ps[1];
        rden_r[r] = 1.f / (((a.x + a.y) + (a.z + a.w)) + ((c.x + c.y) + (c.z + c.w)));
    }

    // ---- PV: wave -> (c-tile = (w&3)*16, K-half = w>>2); 10 ks steps ----
    int cw = (wave & 3) * 16, kh = wave >> 2;
    const unsigned short* vb = vT_h + ((size_t)b * 64 + cw + nlo) * TPAD;
    const unsigned short* pb = P_lds + nlo * 648;   // P row t=nlo
    f32x4 cacc = {0.f, 0.f, 0.f, 0.f};
    int ks0 = kh * 10;
#pragma unroll 5
    for (int i = 0; i < 10; ++i) {
        int ks = ks0 + i;
        bf16x8 pv = *(const bf16x8*)(pb + ks * 32 + quad * 8);   // ds_read_b128
        bf16x8 v8 = *(const bf16x8*)(vb + ks * 32 + quad * 8);
        cacc = mfma_bf16(pv, v8, cacc);
    }
#pragma unroll
    for (int r = 0; r < 4; ++r)
        ctx_sh[kh * 1088 + (cw + nlo) * 17 + quad * 4 + r] = cacc[r] * rden_r[r];
    __syncthreads();

    // ---- epilogue (waves 0-3): out = y + wo @ ctx, wave -> o-tile ----
    if (wave < 4) {
        const unsigned short* woh = wo_h + (size_t)(wave * 16 + nlo) * 64 + quad * 8;
        const unsigned short* wol = wo_l + (size_t)(wave * 16 + nlo) * 64 + quad * 8;
        f32x4 oacc = {0.f, 0.f, 0.f, 0.f};
#pragma unroll
        for (int ks = 0; ks < 2; ++ks) {
            union { unsigned short u[8]; bf16x8 v; } Bc;
#pragma unroll
            for (int j = 0; j < 8; ++j) {
                int c = ks * 32 + quad * 8 + j;
                float cv = ctx_sh[c * 17 + nlo] + ctx_sh[1088 + c * 17 + nlo];
                Bc.u[j] = f32_to_bf16_rne(cv);
            }
            bf16x8 ah = *(const bf16x8*)(woh + ks * 32);
            bf16x8 al = *(const bf16x8*)(wol + ks * 32);
            oacc = mfma_bf16(ah, Bc.v, oacc);
            oacc = mfma_bf16(al, Bc.v, oacc);
        }
        int t_g = t0 + nlo;
        if (t_g < TOUT) {
#pragma unroll
            for (int r = 0; r < 4; ++r) {
                int o = wave * 16 + quad * 4 + r;
                size_t off = ((size_t)b * COUT + o) * TOUT + t_g;
                out[off] = y[off] + oacc[r];
            }
        }
    }
}

// ---------------------------------------------------------------------------
extern "C" void kernel_launch(void* const* d_in, const int* in_sizes, int n_in,
                              void* d_out, int out_size, void* d_ws, size_t ws_size,
                              hipStream_t stream) {
    const float* x        = (const float*)d_in[0];
    const float* conv_w   = (const float*)d_in[1];
    const float* conv_b   = (const float*)d_in[2];
    const float* bn_gamma = (const float*)d_in[3];
    const float* bn_beta  = (const float*)d_in[4];
    const float* bn_mean  = (const float*)d_in[5];
    const float* bn_var   = (const float*)d_in[6];
    const float* wq       = (const float*)d_in[7];
    const float* wk       = (const float*)d_in[8];
    const float* wv       = (const float*)d_in[9];
    const float* wo       = (const float*)d_in[10];
    float* out = (float*)d_out;
    float* ws  = (float*)d_ws;

    // ws layout (float offsets)
    uint4* Afrag4         = (uint4*)ws;                       // 27648 uint4 = 110592 f
    float* scA            = ws + 110656;                      // 64
    float* scB            = ws + 110720;                      // 64
    unsigned short* w3_h  = (unsigned short*)(ws + 110848);   // 12288 us
    unsigned short* w3_l  = (unsigned short*)(ws + 116992);   // 12288 us
    unsigned short* wo_h  = (unsigned short*)(ws + 123136);   // 2048 f
    unsigned short* wo_l  = (unsigned short*)(ws + 125184);   // 2048 f
    float* yb             = ws + 131072;                      // 5,120,000
    unsigned short* q_h   = (unsigned short*)(ws + 5251072);
    unsigned short* k_h   = (unsigned short*)(ws + 7872512);
    unsigned short* vT_h  = (unsigned short*)(ws + 10493952);

    hipLaunchKernelGGL(prep_kernel, dim3(68), dim3(256), 0, stream,
                       conv_w, wq, wk, wv, wo, conv_b, bn_gamma, bn_beta, bn_mean, bn_var,
                       Afrag4, w3_h, w3_l, wo_h, wo_l, scA, scB);
    hipLaunchKernelGGL(conv_kernel, dim3(20, 128), dim3(256), 0, stream,
                       x, Afrag4, scA, scB, w3_h, w3_l, yb, q_h, k_h, vT_h);
    hipLaunchKernelGGL(attn_kernel, dim3(40, 128), dim3(512), 0, stream,
                       q_h, k_h, vT_h, yb, wo_h, wo_l, out);
}